// Round 10
// baseline (526.102 us; speedup 1.0000x reference)
//
#include <hip/hip_runtime.h>
#include <hip/hip_bf16.h>

typedef __attribute__((ext_vector_type(8))) short short8_t;
typedef __attribute__((ext_vector_type(4))) float f32x4;
typedef float f32x4u __attribute__((ext_vector_type(4), aligned(4)));  // 4B-aligned vector load

#define NNODES 50000
#define FIN 1433
#define HID 128
#define NCLS 7
#define KT1 23          // ceil(1433/64)
#define BK 64
#define BM 128

static __device__ __forceinline__ unsigned short f2bf(float f) {
    union { float f; unsigned int u; } v; v.f = f;
    unsigned int u = v.u;
    u += 0x7FFFu + ((u >> 16) & 1u);   // round-to-nearest-even
    return (unsigned short)(u >> 16);
}
static __device__ __forceinline__ float u2f(unsigned int u) {
    union { unsigned int u; float f; } v; v.u = u; return v.f;
}

// ---------------- degree / norm ----------------
__global__ void init_deg(int* deg, int n) {
    int i = blockIdx.x * blockDim.x + threadIdx.x;
    if (i < n) deg[i] = 1;              // self loop
}

// 8 edges per thread, 2x int4 coalesced
__global__ void count_deg8(const int* __restrict__ dst, int E, int* deg) {
    int q = blockIdx.x * 256 + threadIdx.x;
    int i = q * 8;
    if (i + 7 < E) {
        int4 d0 = *(const int4*)(dst + i);
        int4 d1 = *(const int4*)(dst + i + 4);
        atomicAdd(&deg[d0.x], 1); atomicAdd(&deg[d0.y], 1);
        atomicAdd(&deg[d0.z], 1); atomicAdd(&deg[d0.w], 1);
        atomicAdd(&deg[d1.x], 1); atomicAdd(&deg[d1.y], 1);
        atomicAdd(&deg[d1.z], 1); atomicAdd(&deg[d1.w], 1);
    } else if (i < E) {
        for (int e = i; e < E; ++e) atomicAdd(&deg[dst[e]], 1);
    }
}

// ---------------- CSR build (self-loops included, written by scan_apply) ----
__global__ void scan_part(const int* __restrict__ deg, int* __restrict__ blksum, int n) {
    __shared__ int ws[4];
    int i = blockIdx.x * 256 + threadIdx.x;
    int wave = threadIdx.x >> 6, lane = threadIdx.x & 63;
    int s = (i < n) ? deg[i] : 0;
    #pragma unroll
    for (int off = 1; off < 64; off <<= 1) s += __shfl_xor(s, off, 64);
    if (lane == 0) ws[wave] = s;
    __syncthreads();
    if (threadIdx.x == 0) blksum[blockIdx.x] = ws[0] + ws[1] + ws[2] + ws[3];
}

__global__ void scan_block(int* blksum, int nb) {   // one block, nb <= 256
    __shared__ int tmp[256];
    int t = threadIdx.x;
    int v = (t < nb) ? blksum[t] : 0;
    tmp[t] = v;
    __syncthreads();
    #pragma unroll
    for (int off = 1; off < 256; off <<= 1) {
        int u = (t >= off) ? tmp[t - off] : 0;
        __syncthreads();
        tmp[t] += u;
        __syncthreads();
    }
    if (t < nb) blksum[t] = tmp[t] - v;             // exclusive
}

// scan_apply also: dinv = rsqrt(deg), csr[ptr]=self, cursor=ptr+1
__global__ void scan_apply(const int* __restrict__ deg, const int* __restrict__ blksum,
                           int* __restrict__ ptr, int* __restrict__ cursor,
                           float* __restrict__ dinv, int* __restrict__ csr, int n) {
    __shared__ int tmp[256];
    int t = threadIdx.x;
    int i = blockIdx.x * 256 + t;
    int v = (i < n) ? deg[i] : 0;
    tmp[t] = v;
    __syncthreads();
    #pragma unroll
    for (int off = 1; off < 256; off <<= 1) {
        int u = (t >= off) ? tmp[t - off] : 0;
        __syncthreads();
        tmp[t] += u;
        __syncthreads();
    }
    if (i < n) {
        int excl = blksum[blockIdx.x] + tmp[t] - v;
        ptr[i] = excl;
        csr[excl] = i;                  // self loop first (list order irrelevant)
        cursor[i] = excl + 1;
        dinv[i] = rsqrtf((float)v);
    }
}

// 8 edges per thread
__global__ void fill_csr8(const int* __restrict__ src, const int* __restrict__ dst,
                          int E, int* cursor, int* csr) {
    int q = blockIdx.x * 256 + threadIdx.x;
    int i = q * 8;
    if (i + 7 < E) {
        int4 d0 = *(const int4*)(dst + i);
        int4 d1 = *(const int4*)(dst + i + 4);
        int4 s0 = *(const int4*)(src + i);
        int4 s1 = *(const int4*)(src + i + 4);
        csr[atomicAdd(&cursor[d0.x], 1)] = s0.x;
        csr[atomicAdd(&cursor[d0.y], 1)] = s0.y;
        csr[atomicAdd(&cursor[d0.z], 1)] = s0.z;
        csr[atomicAdd(&cursor[d0.w], 1)] = s0.w;
        csr[atomicAdd(&cursor[d1.x], 1)] = s1.x;
        csr[atomicAdd(&cursor[d1.y], 1)] = s1.y;
        csr[atomicAdd(&cursor[d1.z], 1)] = s1.z;
        csr[atomicAdd(&cursor[d1.w], 1)] = s1.w;
    } else if (i < E) {
        for (int e = i; e < E; ++e)
            csr[atomicAdd(&cursor[dst[e]], 1)] = src[e];
    }
}

// ---------------- W1 pack: W1[FIN][HID] f32 -> W1s[KT1][1024 segs][8 bf16]
__global__ void prep_w1(const float* __restrict__ W1, unsigned short* __restrict__ W1s) {
    int tid = blockIdx.x * 256 + threadIdx.x;
    if (tid >= KT1 * 1024) return;
    int kt = tid >> 10, seg = tid & 1023;
    int c = seg & 127, g = seg >> 7;
    int kb = kt * BK + g * 8;
    unsigned int w[4];
    #pragma unroll
    for (int p = 0; p < 4; ++p) {
        int k0 = kb + p * 2, k1 = kb + p * 2 + 1;
        unsigned short lo = (k0 < FIN) ? f2bf(W1[(size_t)k0 * HID + c]) : (unsigned short)0;
        unsigned short hi = (k1 < FIN) ? f2bf(W1[(size_t)k1 * HID + c]) : (unsigned short)0;
        w[p] = (unsigned int)lo | ((unsigned int)hi << 16);
    }
    uint4* dstp = (uint4*)(W1s + (size_t)tid * 8);
    uint4 val; val.x = w[0]; val.y = w[1]; val.z = w[2]; val.w = w[3];
    *dstp = val;
}

// ---------------- GEMM1: h'[M][128] (bf16) = dinv[r] * (x[M][1433] @ W1) ----
// BM=128, BK=64, 512 threads / 8 waves. 3-deep A prefetch (2 reg sets) +
// 3-deep B ring, counted vmcnt, ONE barrier/iter. writeA(t+1) consumes loads
// issued at t-2 (2-iter slack >= HBM latency).
__global__ __launch_bounds__(512, 4) void gemm1(const float* __restrict__ x,
                                                const unsigned short* __restrict__ W1s,
                                                const float* __restrict__ dinv,
                                                unsigned short* __restrict__ h, int M) {
    __shared__ unsigned short As[2][8192];
    __shared__ unsigned short Bs[3][8192];
    const int t = threadIdx.x;
    const int wave = t >> 6, lane = t & 63;
    const int wm = wave >> 1, wn = wave & 1;
    const int r = lane & 15, u = lane >> 4;
    const int rowBase = blockIdx.x * BM;
    f32x4 acc[2][4] = {};

    float4 areg[2][4];   // [set = kt&1][i]

    auto issueA = [&](int kt) {
        int k0 = kt * BK;
        int set = kt & 1;
        #pragma unroll
        for (int i = 0; i < 4; ++i) {
            int quad = i * 512 + t;
            int row = quad >> 4, kq = quad & 15;
            int gr = rowBase + row;
            int gk = k0 + kq * 4;
            if (gr < M && gk + 3 < FIN) {
                f32x4u v = __builtin_nontemporal_load((const f32x4u*)(x + (size_t)gr * FIN + gk));
                areg[set][i].x = v.x; areg[set][i].y = v.y;
                areg[set][i].z = v.z; areg[set][i].w = v.w;
            } else {
                areg[set][i].x = (gr < M && gk + 0 < FIN) ? x[(size_t)gr * FIN + gk + 0] : 0.f;
                areg[set][i].y = (gr < M && gk + 1 < FIN) ? x[(size_t)gr * FIN + gk + 1] : 0.f;
                areg[set][i].z = (gr < M && gk + 2 < FIN) ? x[(size_t)gr * FIN + gk + 2] : 0.f;
                areg[set][i].w = (gr < M && gk + 3 < FIN) ? x[(size_t)gr * FIN + gk + 3] : 0.f;
            }
        }
    };
    auto issueB = [&](int kt, int buf) {
        #pragma unroll
        for (int i = 0; i < 2; ++i) {
            const unsigned short* gp = W1s + ((size_t)kt * 1024 + (size_t)(i * 512 + t)) * 8;
            unsigned short* lp = &Bs[buf][(i * 512 + wave * 64) * 8];
            __builtin_amdgcn_global_load_lds(
                (const __attribute__((address_space(1))) unsigned int*)gp,
                (__attribute__((address_space(3))) unsigned int*)lp, 16, 0, 0);
        }
    };
    auto writeA = [&](int kt) {
        int set = kt & 1;
        #pragma unroll
        for (int i = 0; i < 4; ++i) {
            int quad = i * 512 + t;
            int row = quad >> 4, kq = quad & 15;
            __hip_bfloat162 lo2 = __float22bfloat162_rn(make_float2(areg[set][i].x, areg[set][i].y));
            __hip_bfloat162 hi2 = __float22bfloat162_rn(make_float2(areg[set][i].z, areg[set][i].w));
            unsigned int ulo, uhi;
            __builtin_memcpy(&ulo, &lo2, 4);
            __builtin_memcpy(&uhi, &hi2, 4);
            unsigned long long pk = ((unsigned long long)uhi << 32) | (unsigned long long)ulo;
            int us = row * 64 + ((kq * 4) ^ ((row & 7) << 3));
            *(unsigned long long*)(&As[kt & 1][us]) = pk;
        }
    };
    auto compute = [&](int kt) {
        const int abuf = kt & 1, bbuf = kt % 3;
        short8_t af[2][2], bfr[2][4];
        #pragma unroll
        for (int ks = 0; ks < 2; ++ks) {
            int g = ks * 4 + u;
            #pragma unroll
            for (int mi = 0; mi < 2; ++mi) {
                int row = wm * 32 + mi * 16 + r;
                int us = row * 64 + ((g * 8) ^ ((row & 7) << 3));
                af[ks][mi] = *(const short8_t*)(&As[abuf][us]);
            }
            #pragma unroll
            for (int ni = 0; ni < 4; ++ni) {
                int c = wn * 64 + ni * 16 + r;
                bfr[ks][ni] = *(const short8_t*)(&Bs[bbuf][g * 1024 + c * 8]);
            }
        }
        #pragma unroll
        for (int ks = 0; ks < 2; ++ks)
            #pragma unroll
            for (int mi = 0; mi < 2; ++mi)
                #pragma unroll
                for (int ni = 0; ni < 4; ++ni)
                    acc[mi][ni] = __builtin_amdgcn_mfma_f32_16x16x32_bf16(af[ks][mi], bfr[ks][ni], acc[mi][ni], 0, 0, 0);
    };

    // prologue: A(0) written; A(1),A(2) + B(0),B(1) in flight
    issueA(0);
    issueB(0, 0);
    issueB(1, 1);
    writeA(0);                      // implicit wait on A(0)
    issueA(1);
    issueA(2);
    // outstanding: B0(2) B1(2) A1(8) A2(8) = 20; retire B0:
    asm volatile("s_waitcnt vmcnt(18) lgkmcnt(0)" ::: "memory");
    __builtin_amdgcn_sched_barrier(0);
    __builtin_amdgcn_s_barrier();
    __builtin_amdgcn_sched_barrier(0);

    // main loop: t = 0 .. KT1-4  (issues stay in range; full slack everywhere)
    for (int kt = 0; kt < KT1 - 3; ++kt) {
        issueB(kt + 2, (kt + 2) % 3);   // Bs[(kt-1)%3] free since barrier(kt-1)
        compute(kt);
        writeA(kt + 1);                  // loads issued at kt-2 -> 2-iter slack
        issueA(kt + 3);
        // retire B(t+1): after it remain A(t+2)8 + B(t+2)2 + A(t+3)8 = 18
        asm volatile("s_waitcnt vmcnt(18) lgkmcnt(0)" ::: "memory");
        __builtin_amdgcn_sched_barrier(0);
        __builtin_amdgcn_s_barrier();
        __builtin_amdgcn_sched_barrier(0);
    }
    // tail: t = KT1-3 (full drain from here; ~3 exposed latencies total)
    {
        const int kt = KT1 - 3;
        issueB(kt + 2, (kt + 2) % 3);
        compute(kt);
        writeA(kt + 1);
        __syncthreads();
    }
    {
        const int kt = KT1 - 2;
        compute(kt);
        writeA(kt + 1);
        __syncthreads();
    }
    compute(KT1 - 1);

    // epilogue: C layout col=lane&15, row=(lane>>4)*4+reg; pre-scale by dinv[row]
    #pragma unroll
    for (int mi = 0; mi < 2; ++mi) {
        #pragma unroll
        for (int reg = 0; reg < 4; ++reg) {
            int grow = rowBase + wm * 32 + mi * 16 + u * 4 + reg;
            if (grow < M) {
                float dv = dinv[grow];
                #pragma unroll
                for (int ni = 0; ni < 4; ++ni) {
                    int gcol = wn * 64 + ni * 16 + r;
                    h[(size_t)grow * HID + gcol] = f2bf(dv * acc[mi][ni][reg]);
                }
            }
        }
    }
}

// ---------------- Aggregation 1 + bias + relu + @W2 fused ----------------
__global__ __launch_bounds__(256) void agg1(const unsigned short* __restrict__ h,
                                            const int* __restrict__ ptr,
                                            const int* __restrict__ deg,
                                            const int* __restrict__ csr,
                                            const float* __restrict__ dinv,
                                            const float* __restrict__ b1,
                                            const float* __restrict__ W2,
                                            float* __restrict__ h2s, int n) {
    __shared__ float W2s[HID * NCLS];
    for (int i = threadIdx.x; i < HID * NCLS; i += 256) W2s[i] = W2[i];
    __syncthreads();
    int wave = threadIdx.x >> 6, lane = threadIdx.x & 63;
    int v = blockIdx.x * 4 + wave;
    if (v >= n) return;
    const int fr = lane & 15, g = lane >> 4;
    int p0 = ptr[v];
    int total = deg[v];                 // in-edges + self (all in csr)
    float acc[8] = {};
    #pragma unroll 16
    for (int j = g; j < total; j += 4) {
        int s = csr[p0 + j];
        uint4 q = *(const uint4*)(h + (size_t)s * HID + fr * 8);
        unsigned int w[4] = {q.x, q.y, q.z, q.w};
        #pragma unroll
        for (int p = 0; p < 4; ++p) {
            acc[p * 2 + 0] += u2f(w[p] << 16);          // low bf16
            acc[p * 2 + 1] += u2f(w[p] & 0xffff0000u);  // high bf16
        }
    }
    #pragma unroll
    for (int e = 0; e < 8; ++e) {
        acc[e] += __shfl_xor(acc[e], 16, 64);
        acc[e] += __shfl_xor(acc[e], 32, 64);
    }
    float dv = dinv[v];
    float p[NCLS];
    #pragma unroll
    for (int c = 0; c < NCLS; ++c) p[c] = 0.f;
    #pragma unroll
    for (int e = 0; e < 8; ++e) {
        int f = fr * 8 + e;
        float val = fmaxf(dv * acc[e] + b1[f], 0.f);
        #pragma unroll
        for (int c = 0; c < NCLS; ++c) p[c] += val * W2s[f * NCLS + c];
    }
    #pragma unroll
    for (int off = 8; off >= 1; off >>= 1)
        #pragma unroll
        for (int c = 0; c < NCLS; ++c)
            p[c] += __shfl_xor(p[c], off, 64);
    if (lane == 0) {
        #pragma unroll
        for (int c = 0; c < NCLS; ++c) h2s[(size_t)v * 8 + c] = dv * p[c];  // pre-scaled
        h2s[(size_t)v * 8 + 7] = 0.f;
    }
}

// ---------------- Aggregation 2 + bias ----------------
__global__ __launch_bounds__(256) void agg2(const float* __restrict__ h2s,
                                            const int* __restrict__ ptr,
                                            const int* __restrict__ deg,
                                            const int* __restrict__ csr,
                                            const float* __restrict__ dinv,
                                            const float* __restrict__ b2,
                                            float* __restrict__ out, int n) {
    int wave = threadIdx.x >> 6, lane = threadIdx.x & 63;
    int half = lane >> 5;
    int c = lane & 7, g = (lane >> 3) & 3;
    int v = blockIdx.x * 8 + wave * 2 + half;
    if (v >= n) return;
    int p0 = ptr[v], total = deg[v];
    float acc = 0.f;
    #pragma unroll 8
    for (int j = g; j < total; j += 4) {
        int s = csr[p0 + j];
        acc += h2s[(size_t)s * 8 + c];
    }
    acc += __shfl_xor(acc, 8, 64);
    acc += __shfl_xor(acc, 16, 64);
    if (g == 0 && c < NCLS) out[(size_t)v * NCLS + c] = dinv[v] * acc + b2[c];
}

extern "C" void kernel_launch(void* const* d_in, const int* in_sizes, int n_in,
                              void* d_out, int out_size, void* d_ws, size_t ws_size,
                              hipStream_t stream) {
    const float* x  = (const float*)d_in[0];
    const int*   ei = (const int*)d_in[1];    // int64 in reference but JAX x64-off => int32
    const float* W1 = (const float*)d_in[2];
    const float* b1 = (const float*)d_in[3];
    const float* W2 = (const float*)d_in[4];
    const float* b2 = (const float*)d_in[5];
    float* out = (float*)d_out;

    const int N = NNODES;
    const int E = in_sizes[1] / 2;
    const int* src = ei;
    const int* dst = ei + E;
    const int NB = (N + 255) / 256;           // scan blocks (196 <= 256)

    char* ws = (char*)d_ws;
    size_t off = 0;
    auto alloc = [&](size_t bytes) {
        void* p = ws + off;
        off += (bytes + 255) & ~(size_t)255;
        return p;
    };
    int*   deg    = (int*)alloc((size_t)N * 4);
    float* dinv   = (float*)alloc((size_t)N * 4);
    int*   ptr    = (int*)alloc((size_t)N * 4);
    int*   cursor = (int*)alloc((size_t)N * 4);
    int*   blksum = (int*)alloc((size_t)NB * 4);
    int*   csr    = (int*)alloc((size_t)(E + N) * 4);
    unsigned short* W1s = (unsigned short*)alloc((size_t)KT1 * 1024 * 8 * 2);
    unsigned short* h   = (unsigned short*)alloc((size_t)N * HID * 2);
    float* h2s    = (float*)alloc((size_t)N * 8 * 4);

    init_deg<<<NB, 256, 0, stream>>>(deg, N);
    count_deg8<<<(E / 8 + 255) / 256, 256, 0, stream>>>(dst, E, deg);
    scan_part<<<NB, 256, 0, stream>>>(deg, blksum, N);
    scan_block<<<1, 256, 0, stream>>>(blksum, NB);
    scan_apply<<<NB, 256, 0, stream>>>(deg, blksum, ptr, cursor, dinv, csr, N);
    fill_csr8<<<(E / 8 + 255) / 256, 256, 0, stream>>>(src, dst, E, cursor, csr);
    prep_w1<<<(KT1 * 1024 + 255) / 256, 256, 0, stream>>>(W1, W1s);
    gemm1<<<(N + BM - 1) / BM, 512, 0, stream>>>(x, W1s, dinv, h, N);
    agg1<<<(N + 3) / 4, 256, 0, stream>>>(h, ptr, deg, csr, dinv, b1, W2, h2s, N);
    agg2<<<(N + 7) / 8, 256, 0, stream>>>(h2s, ptr, deg, csr, dinv, b2, out, N);
}

// Round 11
// 416.482 us; speedup vs baseline: 1.2632x; 1.2632x over previous
//
#include <hip/hip_runtime.h>
#include <hip/hip_bf16.h>

typedef __attribute__((ext_vector_type(8))) short short8_t;
typedef __attribute__((ext_vector_type(4))) float f32x4;
typedef float f32x4u __attribute__((ext_vector_type(4), aligned(4)));  // 4B-aligned vector load

#define NNODES 50000
#define FIN 1433
#define HID 128
#define NCLS 7
#define KT1 23          // ceil(1433/64)
#define BK 64
#define BM 128

static __device__ __forceinline__ unsigned short f2bf(float f) {
    union { float f; unsigned int u; } v; v.f = f;
    unsigned int u = v.u;
    u += 0x7FFFu + ((u >> 16) & 1u);   // round-to-nearest-even
    return (unsigned short)(u >> 16);
}
static __device__ __forceinline__ float u2f(unsigned int u) {
    union { unsigned int u; float f; } v; v.u = u; return v.f;
}

// ---------------- degree / norm ----------------
__global__ void init_deg(int* deg, int n) {
    int i = blockIdx.x * blockDim.x + threadIdx.x;
    if (i < n) deg[i] = 1;              // self loop
}

// 8 edges per thread, 2x int4 coalesced
__global__ void count_deg8(const int* __restrict__ dst, int E, int* deg) {
    int q = blockIdx.x * 256 + threadIdx.x;
    int i = q * 8;
    if (i + 7 < E) {
        int4 d0 = *(const int4*)(dst + i);
        int4 d1 = *(const int4*)(dst + i + 4);
        atomicAdd(&deg[d0.x], 1); atomicAdd(&deg[d0.y], 1);
        atomicAdd(&deg[d0.z], 1); atomicAdd(&deg[d0.w], 1);
        atomicAdd(&deg[d1.x], 1); atomicAdd(&deg[d1.y], 1);
        atomicAdd(&deg[d1.z], 1); atomicAdd(&deg[d1.w], 1);
    } else if (i < E) {
        for (int e = i; e < E; ++e) atomicAdd(&deg[dst[e]], 1);
    }
}

// ---------------- CSR build (self-loops included, written by scan_apply) ----
__global__ void scan_part(const int* __restrict__ deg, int* __restrict__ blksum, int n) {
    __shared__ int ws[4];
    int i = blockIdx.x * 256 + threadIdx.x;
    int wave = threadIdx.x >> 6, lane = threadIdx.x & 63;
    int s = (i < n) ? deg[i] : 0;
    #pragma unroll
    for (int off = 1; off < 64; off <<= 1) s += __shfl_xor(s, off, 64);
    if (lane == 0) ws[wave] = s;
    __syncthreads();
    if (threadIdx.x == 0) blksum[blockIdx.x] = ws[0] + ws[1] + ws[2] + ws[3];
}

__global__ void scan_block(int* blksum, int nb) {   // one block, nb <= 256
    __shared__ int tmp[256];
    int t = threadIdx.x;
    int v = (t < nb) ? blksum[t] : 0;
    tmp[t] = v;
    __syncthreads();
    #pragma unroll
    for (int off = 1; off < 256; off <<= 1) {
        int u = (t >= off) ? tmp[t - off] : 0;
        __syncthreads();
        tmp[t] += u;
        __syncthreads();
    }
    if (t < nb) blksum[t] = tmp[t] - v;             // exclusive
}

// scan_apply also: dinv = rsqrt(deg), csr[ptr]=self, cursor=ptr+1
__global__ void scan_apply(const int* __restrict__ deg, const int* __restrict__ blksum,
                           int* __restrict__ ptr, int* __restrict__ cursor,
                           float* __restrict__ dinv, int* __restrict__ csr, int n) {
    __shared__ int tmp[256];
    int t = threadIdx.x;
    int i = blockIdx.x * 256 + t;
    int v = (i < n) ? deg[i] : 0;
    tmp[t] = v;
    __syncthreads();
    #pragma unroll
    for (int off = 1; off < 256; off <<= 1) {
        int u = (t >= off) ? tmp[t - off] : 0;
        __syncthreads();
        tmp[t] += u;
        __syncthreads();
    }
    if (i < n) {
        int excl = blksum[blockIdx.x] + tmp[t] - v;
        ptr[i] = excl;
        csr[excl] = i;                  // self loop first (list order irrelevant)
        cursor[i] = excl + 1;
        dinv[i] = rsqrtf((float)v);
    }
}

// 8 edges per thread
__global__ void fill_csr8(const int* __restrict__ src, const int* __restrict__ dst,
                          int E, int* cursor, int* csr) {
    int q = blockIdx.x * 256 + threadIdx.x;
    int i = q * 8;
    if (i + 7 < E) {
        int4 d0 = *(const int4*)(dst + i);
        int4 d1 = *(const int4*)(dst + i + 4);
        int4 s0 = *(const int4*)(src + i);
        int4 s1 = *(const int4*)(src + i + 4);
        csr[atomicAdd(&cursor[d0.x], 1)] = s0.x;
        csr[atomicAdd(&cursor[d0.y], 1)] = s0.y;
        csr[atomicAdd(&cursor[d0.z], 1)] = s0.z;
        csr[atomicAdd(&cursor[d0.w], 1)] = s0.w;
        csr[atomicAdd(&cursor[d1.x], 1)] = s1.x;
        csr[atomicAdd(&cursor[d1.y], 1)] = s1.y;
        csr[atomicAdd(&cursor[d1.z], 1)] = s1.z;
        csr[atomicAdd(&cursor[d1.w], 1)] = s1.w;
    } else if (i < E) {
        for (int e = i; e < E; ++e)
            csr[atomicAdd(&cursor[dst[e]], 1)] = src[e];
    }
}

// ---------------- W1 pack: W1[FIN][HID] f32 -> W1s[KT1][1024 segs][8 bf16]
__global__ void prep_w1(const float* __restrict__ W1, unsigned short* __restrict__ W1s) {
    int tid = blockIdx.x * 256 + threadIdx.x;
    if (tid >= KT1 * 1024) return;
    int kt = tid >> 10, seg = tid & 1023;
    int c = seg & 127, g = seg >> 7;
    int kb = kt * BK + g * 8;
    unsigned int w[4];
    #pragma unroll
    for (int p = 0; p < 4; ++p) {
        int k0 = kb + p * 2, k1 = kb + p * 2 + 1;
        unsigned short lo = (k0 < FIN) ? f2bf(W1[(size_t)k0 * HID + c]) : (unsigned short)0;
        unsigned short hi = (k1 < FIN) ? f2bf(W1[(size_t)k1 * HID + c]) : (unsigned short)0;
        w[p] = (unsigned int)lo | ((unsigned int)hi << 16);
    }
    uint4* dstp = (uint4*)(W1s + (size_t)tid * 8);
    uint4 val; val.x = w[0]; val.y = w[1]; val.z = w[2]; val.w = w[3];
    *dstp = val;
}

// ---------------- GEMM1: h'[M][128] (bf16) = dinv[r] * (x[M][1433] @ W1) ----
// BM=128, BK=64, 512 threads / 8 waves. 3-deep A prefetch with TWO STATIC
// register sets (areg0/areg1 -- rule #20: no runtime-indexed reg arrays),
// 3-deep B ring, counted vmcnt, ONE barrier/iter, main loop unrolled x2
// so every register-set index is compile-time.
__global__ __launch_bounds__(512, 4) void gemm1(const float* __restrict__ x,
                                                const unsigned short* __restrict__ W1s,
                                                const float* __restrict__ dinv,
                                                unsigned short* __restrict__ h, int M) {
    __shared__ unsigned short As[2][8192];
    __shared__ unsigned short Bs[3][8192];
    const int t = threadIdx.x;
    const int wave = t >> 6, lane = t & 63;
    const int wm = wave >> 1, wn = wave & 1;
    const int r = lane & 15, u = lane >> 4;
    const int rowBase = blockIdx.x * BM;
    f32x4 acc[2][4] = {};

    float4 areg0[4], areg1[4];   // two STATIC prefetch register sets

    auto issueA = [&](int kt, float4 (&areg)[4]) {
        int k0 = kt * BK;
        #pragma unroll
        for (int i = 0; i < 4; ++i) {
            int quad = i * 512 + t;
            int row = quad >> 4, kq = quad & 15;
            int gr = rowBase + row;
            int gk = k0 + kq * 4;
            if (gr < M && gk + 3 < FIN) {
                f32x4u v = __builtin_nontemporal_load((const f32x4u*)(x + (size_t)gr * FIN + gk));
                areg[i].x = v.x; areg[i].y = v.y; areg[i].z = v.z; areg[i].w = v.w;
            } else {
                areg[i].x = (gr < M && gk + 0 < FIN) ? x[(size_t)gr * FIN + gk + 0] : 0.f;
                areg[i].y = (gr < M && gk + 1 < FIN) ? x[(size_t)gr * FIN + gk + 1] : 0.f;
                areg[i].z = (gr < M && gk + 2 < FIN) ? x[(size_t)gr * FIN + gk + 2] : 0.f;
                areg[i].w = (gr < M && gk + 3 < FIN) ? x[(size_t)gr * FIN + gk + 3] : 0.f;
            }
        }
    };
    auto issueB = [&](int kt, int buf) {
        #pragma unroll
        for (int i = 0; i < 2; ++i) {
            const unsigned short* gp = W1s + ((size_t)kt * 1024 + (size_t)(i * 512 + t)) * 8;
            unsigned short* lp = &Bs[buf][(i * 512 + wave * 64) * 8];
            __builtin_amdgcn_global_load_lds(
                (const __attribute__((address_space(1))) unsigned int*)gp,
                (__attribute__((address_space(3))) unsigned int*)lp, 16, 0, 0);
        }
    };
    auto writeA = [&](int abuf, const float4 (&areg)[4]) {
        #pragma unroll
        for (int i = 0; i < 4; ++i) {
            int quad = i * 512 + t;
            int row = quad >> 4, kq = quad & 15;
            __hip_bfloat162 lo2 = __float22bfloat162_rn(make_float2(areg[i].x, areg[i].y));
            __hip_bfloat162 hi2 = __float22bfloat162_rn(make_float2(areg[i].z, areg[i].w));
            unsigned int ulo, uhi;
            __builtin_memcpy(&ulo, &lo2, 4);
            __builtin_memcpy(&uhi, &hi2, 4);
            unsigned long long pk = ((unsigned long long)uhi << 32) | (unsigned long long)ulo;
            int us = row * 64 + ((kq * 4) ^ ((row & 7) << 3));
            *(unsigned long long*)(&As[abuf][us]) = pk;
        }
    };
    auto compute = [&](int kt) {
        const int abuf = kt & 1, bbuf = kt % 3;
        short8_t af[2][2], bfr[2][4];
        #pragma unroll
        for (int ks = 0; ks < 2; ++ks) {
            int g = ks * 4 + u;
            #pragma unroll
            for (int mi = 0; mi < 2; ++mi) {
                int row = wm * 32 + mi * 16 + r;
                int us = row * 64 + ((g * 8) ^ ((row & 7) << 3));
                af[ks][mi] = *(const short8_t*)(&As[abuf][us]);
            }
            #pragma unroll
            for (int ni = 0; ni < 4; ++ni) {
                int c = wn * 64 + ni * 16 + r;
                bfr[ks][ni] = *(const short8_t*)(&Bs[bbuf][g * 1024 + c * 8]);
            }
        }
        #pragma unroll
        for (int ks = 0; ks < 2; ++ks)
            #pragma unroll
            for (int mi = 0; mi < 2; ++mi)
                #pragma unroll
                for (int ni = 0; ni < 4; ++ni)
                    acc[mi][ni] = __builtin_amdgcn_mfma_f32_16x16x32_bf16(af[ks][mi], bfr[ks][ni], acc[mi][ni], 0, 0, 0);
    };

    // prologue: A(0) staged to LDS; A(1)->areg1, A(2)->areg0 + B(0),B(1) in flight
    issueA(0, areg0);
    issueB(0, 0);
    issueB(1, 1);
    writeA(0, areg0);               // implicit wait on A(0) loads
    issueA(1, areg1);
    issueA(2, areg0);
    // outstanding: B0(2) B1(2) A1(8) A2(8) = 20; retire B0:
    asm volatile("s_waitcnt vmcnt(18) lgkmcnt(0)" ::: "memory");
    __builtin_amdgcn_sched_barrier(0);
    __builtin_amdgcn_s_barrier();
    __builtin_amdgcn_sched_barrier(0);

    // main loop, unrolled x2 for static reg-set parity: kt = 0..KT1-4 (20 iters)
    for (int kt = 0; kt < KT1 - 3; kt += 2) {
        // even sub-iter: writeA(kt+1) reads areg1; issueA(kt+3) refills areg1
        issueB(kt + 2, (kt + 2) % 3);
        compute(kt);
        writeA((kt + 1) & 1, areg1);
        issueA(kt + 3, areg1);
        asm volatile("s_waitcnt vmcnt(18) lgkmcnt(0)" ::: "memory");
        __builtin_amdgcn_sched_barrier(0);
        __builtin_amdgcn_s_barrier();
        __builtin_amdgcn_sched_barrier(0);
        // odd sub-iter: writeA(kt+2) reads areg0; issueA(kt+4) refills areg0
        issueB(kt + 3, (kt + 3) % 3);
        compute(kt + 1);
        writeA((kt + 2) & 1, areg0);
        issueA(kt + 4, areg0);
        asm volatile("s_waitcnt vmcnt(18) lgkmcnt(0)" ::: "memory");
        __builtin_amdgcn_sched_barrier(0);
        __builtin_amdgcn_s_barrier();
        __builtin_amdgcn_sched_barrier(0);
    }
    // tail: kt = 20 (even), 21, 22 -- full drain
    {
        const int kt = KT1 - 3;          // 20
        issueB(kt + 2, (kt + 2) % 3);
        compute(kt);
        writeA((kt + 1) & 1, areg1);     // A(21) lives in areg1
        __syncthreads();
    }
    {
        const int kt = KT1 - 2;          // 21
        compute(kt);
        writeA((kt + 1) & 1, areg0);     // A(22) lives in areg0
        __syncthreads();
    }
    compute(KT1 - 1);                    // 22

    // epilogue: C layout col=lane&15, row=(lane>>4)*4+reg; pre-scale by dinv[row]
    #pragma unroll
    for (int mi = 0; mi < 2; ++mi) {
        #pragma unroll
        for (int reg = 0; reg < 4; ++reg) {
            int grow = rowBase + wm * 32 + mi * 16 + u * 4 + reg;
            if (grow < M) {
                float dv = dinv[grow];
                #pragma unroll
                for (int ni = 0; ni < 4; ++ni) {
                    int gcol = wn * 64 + ni * 16 + r;
                    h[(size_t)grow * HID + gcol] = f2bf(dv * acc[mi][ni][reg]);
                }
            }
        }
    }
}

// ---------------- Aggregation 1 + bias + relu + @W2 fused ----------------
__global__ __launch_bounds__(256) void agg1(const unsigned short* __restrict__ h,
                                            const int* __restrict__ ptr,
                                            const int* __restrict__ deg,
                                            const int* __restrict__ csr,
                                            const float* __restrict__ dinv,
                                            const float* __restrict__ b1,
                                            const float* __restrict__ W2,
                                            float* __restrict__ h2s, int n) {
    __shared__ float W2s[HID * NCLS];
    for (int i = threadIdx.x; i < HID * NCLS; i += 256) W2s[i] = W2[i];
    __syncthreads();
    int wave = threadIdx.x >> 6, lane = threadIdx.x & 63;
    int v = blockIdx.x * 4 + wave;
    if (v >= n) return;
    const int fr = lane & 15, g = lane >> 4;
    int p0 = ptr[v];
    int total = deg[v];                 // in-edges + self (all in csr)
    float acc[8] = {};
    #pragma unroll 16
    for (int j = g; j < total; j += 4) {
        int s = csr[p0 + j];
        uint4 q = *(const uint4*)(h + (size_t)s * HID + fr * 8);
        unsigned int w[4] = {q.x, q.y, q.z, q.w};
        #pragma unroll
        for (int p = 0; p < 4; ++p) {
            acc[p * 2 + 0] += u2f(w[p] << 16);          // low bf16
            acc[p * 2 + 1] += u2f(w[p] & 0xffff0000u);  // high bf16
        }
    }
    #pragma unroll
    for (int e = 0; e < 8; ++e) {
        acc[e] += __shfl_xor(acc[e], 16, 64);
        acc[e] += __shfl_xor(acc[e], 32, 64);
    }
    float dv = dinv[v];
    float p[NCLS];
    #pragma unroll
    for (int c = 0; c < NCLS; ++c) p[c] = 0.f;
    #pragma unroll
    for (int e = 0; e < 8; ++e) {
        int f = fr * 8 + e;
        float val = fmaxf(dv * acc[e] + b1[f], 0.f);
        #pragma unroll
        for (int c = 0; c < NCLS; ++c) p[c] += val * W2s[f * NCLS + c];
    }
    #pragma unroll
    for (int off = 8; off >= 1; off >>= 1)
        #pragma unroll
        for (int c = 0; c < NCLS; ++c)
            p[c] += __shfl_xor(p[c], off, 64);
    if (lane == 0) {
        #pragma unroll
        for (int c = 0; c < NCLS; ++c) h2s[(size_t)v * 8 + c] = dv * p[c];  // pre-scaled
        h2s[(size_t)v * 8 + 7] = 0.f;
    }
}

// ---------------- Aggregation 2 + bias ----------------
__global__ __launch_bounds__(256) void agg2(const float* __restrict__ h2s,
                                            const int* __restrict__ ptr,
                                            const int* __restrict__ deg,
                                            const int* __restrict__ csr,
                                            const float* __restrict__ dinv,
                                            const float* __restrict__ b2,
                                            float* __restrict__ out, int n) {
    int wave = threadIdx.x >> 6, lane = threadIdx.x & 63;
    int half = lane >> 5;
    int c = lane & 7, g = (lane >> 3) & 3;
    int v = blockIdx.x * 8 + wave * 2 + half;
    if (v >= n) return;
    int p0 = ptr[v], total = deg[v];
    float acc = 0.f;
    #pragma unroll 8
    for (int j = g; j < total; j += 4) {
        int s = csr[p0 + j];
        acc += h2s[(size_t)s * 8 + c];
    }
    acc += __shfl_xor(acc, 8, 64);
    acc += __shfl_xor(acc, 16, 64);
    if (g == 0 && c < NCLS) out[(size_t)v * NCLS + c] = dinv[v] * acc + b2[c];
}

extern "C" void kernel_launch(void* const* d_in, const int* in_sizes, int n_in,
                              void* d_out, int out_size, void* d_ws, size_t ws_size,
                              hipStream_t stream) {
    const float* x  = (const float*)d_in[0];
    const int*   ei = (const int*)d_in[1];    // int64 in reference but JAX x64-off => int32
    const float* W1 = (const float*)d_in[2];
    const float* b1 = (const float*)d_in[3];
    const float* W2 = (const float*)d_in[4];
    const float* b2 = (const float*)d_in[5];
    float* out = (float*)d_out;

    const int N = NNODES;
    const int E = in_sizes[1] / 2;
    const int* src = ei;
    const int* dst = ei + E;
    const int NB = (N + 255) / 256;           // scan blocks (196 <= 256)

    char* ws = (char*)d_ws;
    size_t off = 0;
    auto alloc = [&](size_t bytes) {
        void* p = ws + off;
        off += (bytes + 255) & ~(size_t)255;
        return p;
    };
    int*   deg    = (int*)alloc((size_t)N * 4);
    float* dinv   = (float*)alloc((size_t)N * 4);
    int*   ptr    = (int*)alloc((size_t)N * 4);
    int*   cursor = (int*)alloc((size_t)N * 4);
    int*   blksum = (int*)alloc((size_t)NB * 4);
    int*   csr    = (int*)alloc((size_t)(E + N) * 4);
    unsigned short* W1s = (unsigned short*)alloc((size_t)KT1 * 1024 * 8 * 2);
    unsigned short* h   = (unsigned short*)alloc((size_t)N * HID * 2);
    float* h2s    = (float*)alloc((size_t)N * 8 * 4);

    init_deg<<<NB, 256, 0, stream>>>(deg, N);
    count_deg8<<<(E / 8 + 255) / 256, 256, 0, stream>>>(dst, E, deg);
    scan_part<<<NB, 256, 0, stream>>>(deg, blksum, N);
    scan_block<<<1, 256, 0, stream>>>(blksum, NB);
    scan_apply<<<NB, 256, 0, stream>>>(deg, blksum, ptr, cursor, dinv, csr, N);
    fill_csr8<<<(E / 8 + 255) / 256, 256, 0, stream>>>(src, dst, E, cursor, csr);
    prep_w1<<<(KT1 * 1024 + 255) / 256, 256, 0, stream>>>(W1, W1s);
    gemm1<<<(N + BM - 1) / BM, 512, 0, stream>>>(x, W1s, dinv, h, N);
    agg1<<<(N + 3) / 4, 256, 0, stream>>>(h, ptr, deg, csr, dinv, b1, W2, h2s, N);
    agg2<<<(N + 7) / 8, 256, 0, stream>>>(h2s, ptr, deg, csr, dinv, b2, out, N);
}

// Round 12
// 373.397 us; speedup vs baseline: 1.4090x; 1.1154x over previous
//
#include <hip/hip_runtime.h>
#include <hip/hip_bf16.h>

typedef __attribute__((ext_vector_type(8))) short short8_t;
typedef __attribute__((ext_vector_type(4))) float f32x4;
typedef float f32x4u __attribute__((ext_vector_type(4), aligned(4)));  // 4B-aligned vector load

#define NNODES 50000
#define FIN 1433
#define HID 128
#define NCLS 7
#define KT1 23          // ceil(1433/64)
#define BK 64
#define BM 128

static __device__ __forceinline__ unsigned short f2bf(float f) {
    union { float f; unsigned int u; } v; v.f = f;
    unsigned int u = v.u;
    u += 0x7FFFu + ((u >> 16) & 1u);   // round-to-nearest-even
    return (unsigned short)(u >> 16);
}
static __device__ __forceinline__ float u2f(unsigned int u) {
    union { unsigned int u; float f; } v; v.u = u; return v.f;
}

// ---------------- W1 pack: W1[FIN][HID] f32 -> W1s[KT1][1024 segs][8 bf16]
__global__ void prep_w1(const float* __restrict__ W1, unsigned short* __restrict__ W1s) {
    int tid = blockIdx.x * 512 + threadIdx.x;
    if (tid >= KT1 * 1024) return;
    int kt = tid >> 10, seg = tid & 1023;
    int c = seg & 127, g = seg >> 7;
    int kb = kt * BK + g * 8;
    unsigned int w[4];
    #pragma unroll
    for (int p = 0; p < 4; ++p) {
        int k0 = kb + p * 2, k1 = kb + p * 2 + 1;
        unsigned short lo = (k0 < FIN) ? f2bf(W1[(size_t)k0 * HID + c]) : (unsigned short)0;
        unsigned short hi = (k1 < FIN) ? f2bf(W1[(size_t)k1 * HID + c]) : (unsigned short)0;
        w[p] = (unsigned int)lo | ((unsigned int)hi << 16);
    }
    uint4* dstp = (uint4*)(W1s + (size_t)tid * 8);
    uint4 val; val.x = w[0]; val.y = w[1]; val.z = w[2]; val.w = w[3];
    *dstp = val;
}

// ---------------- FAT kernel: gemm blocks [0,gb) || count blocks [gb, grid) --
// GEMM: h[M][128] (bf16) = x[M][1433] @ W1  (NO dinv prescale -> independent
// of the edge pipeline, so degree counting runs concurrently on other blocks).
// R9-verified pipeline: 1-deep A reg-stage, 3-deep B ring via global_load_lds,
// counted vmcnt(6) (ledger: B(t+1)2 + A(t+2)4 + B(t+2)2 = 8 outstanding,
// retire 2, keep 6 in flight across the barrier).
// COUNT: deg[dst[e]]++ (deg pre-zeroed; self-loop accounted as deg+1 later).
__global__ __launch_bounds__(512, 4) void gemm_count(const float* __restrict__ x,
                                                     const unsigned short* __restrict__ W1s,
                                                     unsigned short* __restrict__ h, int M,
                                                     const int* __restrict__ dst, int E,
                                                     int* __restrict__ deg, int gb) {
    __shared__ unsigned short As[2][8192];
    __shared__ unsigned short Bs[3][8192];

    if (blockIdx.x >= gb) {
        // ---- count blocks: 512 threads x 8 edges ----
        int bid = blockIdx.x - gb;
        int i = (bid * 512 + (int)threadIdx.x) * 8;
        if (i + 7 < E) {
            int4 d0 = *(const int4*)(dst + i);
            int4 d1 = *(const int4*)(dst + i + 4);
            atomicAdd(&deg[d0.x], 1); atomicAdd(&deg[d0.y], 1);
            atomicAdd(&deg[d0.z], 1); atomicAdd(&deg[d0.w], 1);
            atomicAdd(&deg[d1.x], 1); atomicAdd(&deg[d1.y], 1);
            atomicAdd(&deg[d1.z], 1); atomicAdd(&deg[d1.w], 1);
        } else if (i < E) {
            for (int e = i; e < E; ++e) atomicAdd(&deg[dst[e]], 1);
        }
        return;
    }

    // ---- gemm blocks ----
    const int t = threadIdx.x;
    const int wave = t >> 6, lane = t & 63;
    const int wm = wave >> 1, wn = wave & 1;
    const int r = lane & 15, u = lane >> 4;
    const int rowBase = blockIdx.x * BM;
    f32x4 acc[2][4] = {};

    float4 areg[4];

    auto issueA = [&](int kt) {
        int k0 = kt * BK;
        #pragma unroll
        for (int i = 0; i < 4; ++i) {
            int quad = i * 512 + t;
            int row = quad >> 4, kq = quad & 15;
            int gr = rowBase + row;
            int gk = k0 + kq * 4;
            if (gr < M && gk + 3 < FIN) {
                f32x4u v = __builtin_nontemporal_load((const f32x4u*)(x + (size_t)gr * FIN + gk));
                areg[i].x = v.x; areg[i].y = v.y; areg[i].z = v.z; areg[i].w = v.w;
            } else {
                areg[i].x = (gr < M && gk + 0 < FIN) ? x[(size_t)gr * FIN + gk + 0] : 0.f;
                areg[i].y = (gr < M && gk + 1 < FIN) ? x[(size_t)gr * FIN + gk + 1] : 0.f;
                areg[i].z = (gr < M && gk + 2 < FIN) ? x[(size_t)gr * FIN + gk + 2] : 0.f;
                areg[i].w = (gr < M && gk + 3 < FIN) ? x[(size_t)gr * FIN + gk + 3] : 0.f;
            }
        }
    };
    auto issueB = [&](int kt, int buf) {
        #pragma unroll
        for (int i = 0; i < 2; ++i) {
            const unsigned short* gp = W1s + ((size_t)kt * 1024 + (size_t)(i * 512 + t)) * 8;
            unsigned short* lp = &Bs[buf][(i * 512 + wave * 64) * 8];
            __builtin_amdgcn_global_load_lds(
                (const __attribute__((address_space(1))) unsigned int*)gp,
                (__attribute__((address_space(3))) unsigned int*)lp, 16, 0, 0);
        }
    };
    auto writeA = [&](int buf) {
        #pragma unroll
        for (int i = 0; i < 4; ++i) {
            int quad = i * 512 + t;
            int row = quad >> 4, kq = quad & 15;
            __hip_bfloat162 lo2 = __float22bfloat162_rn(make_float2(areg[i].x, areg[i].y));
            __hip_bfloat162 hi2 = __float22bfloat162_rn(make_float2(areg[i].z, areg[i].w));
            unsigned int ulo, uhi;
            __builtin_memcpy(&ulo, &lo2, 4);
            __builtin_memcpy(&uhi, &hi2, 4);
            unsigned long long pk = ((unsigned long long)uhi << 32) | (unsigned long long)ulo;
            int us = row * 64 + ((kq * 4) ^ ((row & 7) << 3));
            *(unsigned long long*)(&As[buf][us]) = pk;
        }
    };
    auto compute = [&](int abuf, int bbuf) {
        short8_t af[2][2], bfr[2][4];
        #pragma unroll
        for (int ks = 0; ks < 2; ++ks) {
            int g = ks * 4 + u;
            #pragma unroll
            for (int mi = 0; mi < 2; ++mi) {
                int row = wm * 32 + mi * 16 + r;
                int us = row * 64 + ((g * 8) ^ ((row & 7) << 3));
                af[ks][mi] = *(const short8_t*)(&As[abuf][us]);
            }
            #pragma unroll
            for (int ni = 0; ni < 4; ++ni) {
                int c = wn * 64 + ni * 16 + r;
                bfr[ks][ni] = *(const short8_t*)(&Bs[bbuf][g * 1024 + c * 8]);
            }
        }
        #pragma unroll
        for (int ks = 0; ks < 2; ++ks)
            #pragma unroll
            for (int mi = 0; mi < 2; ++mi)
                #pragma unroll
                for (int ni = 0; ni < 4; ++ni)
                    acc[mi][ni] = __builtin_amdgcn_mfma_f32_16x16x32_bf16(af[ks][mi], bfr[ks][ni], acc[mi][ni], 0, 0, 0);
    };

    // prologue: tile 0 staged, tile 1 in flight
    issueA(0); issueB(0, 0);
    writeA(0);                       // waits A(0); B(0) may remain in flight
    issueA(1); issueB(1, 1);
    asm volatile("s_waitcnt vmcnt(6) lgkmcnt(0)" ::: "memory");  // retire B(0); A(1)+B(1)=6 in flight
    __builtin_amdgcn_sched_barrier(0);
    __builtin_amdgcn_s_barrier();
    __builtin_amdgcn_sched_barrier(0);

    for (int kt = 0; kt < KT1 - 2; ++kt) {
        compute(kt & 1, kt % 3);
        writeA((kt + 1) & 1);        // waits A(t+1) (issued last iter)
        issueA(kt + 2);
        issueB(kt + 2, (kt + 2) % 3);
        // outstanding: B(t+1)2 + A(t+2)4 + B(t+2)2 = 8 -> retire B(t+1)
        asm volatile("s_waitcnt vmcnt(6) lgkmcnt(0)" ::: "memory");
        __builtin_amdgcn_sched_barrier(0);
        __builtin_amdgcn_s_barrier();
        __builtin_amdgcn_sched_barrier(0);
    }
    {
        const int kt = KT1 - 2;
        compute(kt & 1, kt % 3);
        writeA((kt + 1) & 1);
        __syncthreads();
    }
    compute((KT1 - 1) & 1, (KT1 - 1) % 3);

    // epilogue: C layout col=lane&15, row=(lane>>4)*4+reg (raw, no dinv)
    #pragma unroll
    for (int mi = 0; mi < 2; ++mi) {
        #pragma unroll
        for (int reg = 0; reg < 4; ++reg) {
            int grow = rowBase + wm * 32 + mi * 16 + u * 4 + reg;
            if (grow < M) {
                #pragma unroll
                for (int ni = 0; ni < 4; ++ni) {
                    int gcol = wn * 64 + ni * 16 + r;
                    h[(size_t)grow * HID + gcol] = f2bf(acc[mi][ni][reg]);
                }
            }
        }
    }
}

// ---------------- CSR build (deg = in-edges; +1 self handled here) ----------
__global__ void scan_part(const int* __restrict__ deg, int* __restrict__ blksum, int n) {
    __shared__ int ws[4];
    int i = blockIdx.x * 256 + threadIdx.x;
    int wave = threadIdx.x >> 6, lane = threadIdx.x & 63;
    int s = (i < n) ? deg[i] + 1 : 0;
    #pragma unroll
    for (int off = 1; off < 64; off <<= 1) s += __shfl_xor(s, off, 64);
    if (lane == 0) ws[wave] = s;
    __syncthreads();
    if (threadIdx.x == 0) blksum[blockIdx.x] = ws[0] + ws[1] + ws[2] + ws[3];
}

__global__ void scan_block(int* blksum, int nb) {   // one block, nb <= 256
    __shared__ int tmp[256];
    int t = threadIdx.x;
    int v = (t < nb) ? blksum[t] : 0;
    tmp[t] = v;
    __syncthreads();
    #pragma unroll
    for (int off = 1; off < 256; off <<= 1) {
        int u = (t >= off) ? tmp[t - off] : 0;
        __syncthreads();
        tmp[t] += u;
        __syncthreads();
    }
    if (t < nb) blksum[t] = tmp[t] - v;             // exclusive
}

// scan_apply: ptr/cursor, dinv = rsqrt(deg+1), csr[ptr]=self, cursor=ptr+1
__global__ void scan_apply(const int* __restrict__ deg, const int* __restrict__ blksum,
                           int* __restrict__ ptr, int* __restrict__ cursor,
                           float* __restrict__ dinv, int* __restrict__ csr, int n) {
    __shared__ int tmp[256];
    int t = threadIdx.x;
    int i = blockIdx.x * 256 + t;
    int v = (i < n) ? deg[i] + 1 : 0;
    tmp[t] = v;
    __syncthreads();
    #pragma unroll
    for (int off = 1; off < 256; off <<= 1) {
        int u = (t >= off) ? tmp[t - off] : 0;
        __syncthreads();
        tmp[t] += u;
        __syncthreads();
    }
    if (i < n) {
        int excl = blksum[blockIdx.x] + tmp[t] - v;
        ptr[i] = excl;
        csr[excl] = i;                  // self loop first (list order irrelevant)
        cursor[i] = excl + 1;
        dinv[i] = rsqrtf((float)v);
    }
}

// 8 edges per thread
__global__ void fill_csr8(const int* __restrict__ src, const int* __restrict__ dst,
                          int E, int* cursor, int* csr) {
    int q = blockIdx.x * 256 + threadIdx.x;
    int i = q * 8;
    if (i + 7 < E) {
        int4 d0 = *(const int4*)(dst + i);
        int4 d1 = *(const int4*)(dst + i + 4);
        int4 s0 = *(const int4*)(src + i);
        int4 s1 = *(const int4*)(src + i + 4);
        csr[atomicAdd(&cursor[d0.x], 1)] = s0.x;
        csr[atomicAdd(&cursor[d0.y], 1)] = s0.y;
        csr[atomicAdd(&cursor[d0.z], 1)] = s0.z;
        csr[atomicAdd(&cursor[d0.w], 1)] = s0.w;
        csr[atomicAdd(&cursor[d1.x], 1)] = s1.x;
        csr[atomicAdd(&cursor[d1.y], 1)] = s1.y;
        csr[atomicAdd(&cursor[d1.z], 1)] = s1.z;
        csr[atomicAdd(&cursor[d1.w], 1)] = s1.w;
    } else if (i < E) {
        for (int e = i; e < E; ++e)
            csr[atomicAdd(&cursor[dst[e]], 1)] = src[e];
    }
}

// ---------------- Aggregation 1 + bias + relu + @W2 fused ----------------
// h is RAW x@W1 bf16; per-edge scale dinv[s] applied here (fp32, broadcast
// load across the 16 feature-lanes of each row-group).
__global__ __launch_bounds__(256) void agg1(const unsigned short* __restrict__ h,
                                            const int* __restrict__ ptr,
                                            const int* __restrict__ deg,
                                            const int* __restrict__ csr,
                                            const float* __restrict__ dinv,
                                            const float* __restrict__ b1,
                                            const float* __restrict__ W2,
                                            float* __restrict__ h2s, int n) {
    __shared__ float W2s[HID * NCLS];
    for (int i = threadIdx.x; i < HID * NCLS; i += 256) W2s[i] = W2[i];
    __syncthreads();
    int wave = threadIdx.x >> 6, lane = threadIdx.x & 63;
    int v = blockIdx.x * 4 + wave;
    if (v >= n) return;
    const int fr = lane & 15, g = lane >> 4;
    int p0 = ptr[v];
    int total = deg[v] + 1;             // in-edges + self (all in csr)
    float acc[8] = {};
    #pragma unroll 16
    for (int j = g; j < total; j += 4) {
        int s = csr[p0 + j];
        float ds = dinv[s];
        uint4 q = *(const uint4*)(h + (size_t)s * HID + fr * 8);
        unsigned int w[4] = {q.x, q.y, q.z, q.w};
        #pragma unroll
        for (int p = 0; p < 4; ++p) {
            acc[p * 2 + 0] += ds * u2f(w[p] << 16);          // low bf16
            acc[p * 2 + 1] += ds * u2f(w[p] & 0xffff0000u);  // high bf16
        }
    }
    #pragma unroll
    for (int e = 0; e < 8; ++e) {
        acc[e] += __shfl_xor(acc[e], 16, 64);
        acc[e] += __shfl_xor(acc[e], 32, 64);
    }
    float dv = dinv[v];
    float p[NCLS];
    #pragma unroll
    for (int c = 0; c < NCLS; ++c) p[c] = 0.f;
    #pragma unroll
    for (int e = 0; e < 8; ++e) {
        int f = fr * 8 + e;
        float val = fmaxf(dv * acc[e] + b1[f], 0.f);
        #pragma unroll
        for (int c = 0; c < NCLS; ++c) p[c] += val * W2s[f * NCLS + c];
    }
    #pragma unroll
    for (int off = 8; off >= 1; off >>= 1)
        #pragma unroll
        for (int c = 0; c < NCLS; ++c)
            p[c] += __shfl_xor(p[c], off, 64);
    if (lane == 0) {
        #pragma unroll
        for (int c = 0; c < NCLS; ++c) h2s[(size_t)v * 8 + c] = dv * p[c];  // pre-scaled
        h2s[(size_t)v * 8 + 7] = 0.f;
    }
}

// ---------------- Aggregation 2 + bias ----------------
__global__ __launch_bounds__(256) void agg2(const float* __restrict__ h2s,
                                            const int* __restrict__ ptr,
                                            const int* __restrict__ deg,
                                            const int* __restrict__ csr,
                                            const float* __restrict__ dinv,
                                            const float* __restrict__ b2,
                                            float* __restrict__ out, int n) {
    int wave = threadIdx.x >> 6, lane = threadIdx.x & 63;
    int half = lane >> 5;
    int c = lane & 7, g = (lane >> 3) & 3;
    int v = blockIdx.x * 8 + wave * 2 + half;
    if (v >= n) return;
    int p0 = ptr[v], total = deg[v] + 1;
    float acc = 0.f;
    #pragma unroll 8
    for (int j = g; j < total; j += 4) {
        int s = csr[p0 + j];
        acc += h2s[(size_t)s * 8 + c];
    }
    acc += __shfl_xor(acc, 8, 64);
    acc += __shfl_xor(acc, 16, 64);
    if (g == 0 && c < NCLS) out[(size_t)v * NCLS + c] = dinv[v] * acc + b2[c];
}

extern "C" void kernel_launch(void* const* d_in, const int* in_sizes, int n_in,
                              void* d_out, int out_size, void* d_ws, size_t ws_size,
                              hipStream_t stream) {
    const float* x  = (const float*)d_in[0];
    const int*   ei = (const int*)d_in[1];    // int64 in reference but JAX x64-off => int32
    const float* W1 = (const float*)d_in[2];
    const float* b1 = (const float*)d_in[3];
    const float* W2 = (const float*)d_in[4];
    const float* b2 = (const float*)d_in[5];
    float* out = (float*)d_out;

    const int N = NNODES;
    const int E = in_sizes[1] / 2;
    const int* src = ei;
    const int* dst = ei + E;
    const int NB = (N + 255) / 256;           // scan blocks (196 <= 256)
    const int GB = (N + BM - 1) / BM;         // gemm blocks (391)
    const int CB = (E + 4095) / 4096;         // count blocks (512t x 8 edges)

    char* ws = (char*)d_ws;
    size_t off = 0;
    auto alloc = [&](size_t bytes) {
        void* p = ws + off;
        off += (bytes + 255) & ~(size_t)255;
        return p;
    };
    int*   deg    = (int*)alloc((size_t)N * 4);
    float* dinv   = (float*)alloc((size_t)N * 4);
    int*   ptr    = (int*)alloc((size_t)N * 4);
    int*   cursor = (int*)alloc((size_t)N * 4);
    int*   blksum = (int*)alloc((size_t)NB * 4);
    int*   csr    = (int*)alloc((size_t)(E + N) * 4);
    unsigned short* W1s = (unsigned short*)alloc((size_t)KT1 * 1024 * 8 * 2);
    unsigned short* h   = (unsigned short*)alloc((size_t)N * HID * 2);
    float* h2s    = (float*)alloc((size_t)N * 8 * 4);

    hipMemsetAsync(deg, 0, (size_t)N * 4, stream);
    prep_w1<<<(KT1 * 1024 + 511) / 512, 512, 0, stream>>>(W1, W1s);
    gemm_count<<<GB + CB, 512, 0, stream>>>(x, W1s, h, N, dst, E, deg, GB);
    scan_part<<<NB, 256, 0, stream>>>(deg, blksum, N);
    scan_block<<<1, 256, 0, stream>>>(blksum, NB);
    scan_apply<<<NB, 256, 0, stream>>>(deg, blksum, ptr, cursor, dinv, csr, N);
    fill_csr8<<<(E / 8 + 255) / 256, 256, 0, stream>>>(src, dst, E, cursor, csr);
    agg1<<<(N + 3) / 4, 256, 0, stream>>>(h, ptr, deg, csr, dinv, b1, W2, h2s, N);
    agg2<<<(N + 7) / 8, 256, 0, stream>>>(h2s, ptr, deg, csr, dinv, b2, out, N);
}

// Round 13
// 247.422 us; speedup vs baseline: 2.1263x; 1.5091x over previous
//
#include <hip/hip_runtime.h>
#include <hip/hip_bf16.h>

typedef __attribute__((ext_vector_type(8))) short short8_t;
typedef __attribute__((ext_vector_type(4))) float f32x4;
typedef float f32x4u __attribute__((ext_vector_type(4), aligned(4)));  // 4B-aligned vector load

#define NNODES 50000
#define FIN 1433
#define HID 128
#define NCLS 7
#define KT1 23          // ceil(1433/64)
#define BK 64
#define BM 128
#define CAP 96          // fixed CSR slots/node; Poisson(32) => P(deg>96) ~ 0; exact via ovf

static __device__ __forceinline__ unsigned short f2bf(float f) {
    union { float f; unsigned int u; } v; v.f = f;
    unsigned int u = v.u;
    u += 0x7FFFu + ((u >> 16) & 1u);   // round-to-nearest-even
    return (unsigned short)(u >> 16);
}
static __device__ __forceinline__ float u2f(unsigned int u) {
    union { unsigned int u; float f; } v; v.u = u; return v.f;
}

// ---------------- W1 pack: W1[FIN][HID] f32 -> W1s[KT1][1024 segs][8 bf16]
__global__ void prep_w1(const float* __restrict__ W1, unsigned short* __restrict__ W1s) {
    int tid = blockIdx.x * 512 + threadIdx.x;
    if (tid >= KT1 * 1024) return;
    int kt = tid >> 10, seg = tid & 1023;
    int c = seg & 127, g = seg >> 7;
    int kb = kt * BK + g * 8;
    unsigned int w[4];
    #pragma unroll
    for (int p = 0; p < 4; ++p) {
        int k0 = kb + p * 2, k1 = kb + p * 2 + 1;
        unsigned short lo = (k0 < FIN) ? f2bf(W1[(size_t)k0 * HID + c]) : (unsigned short)0;
        unsigned short hi = (k1 < FIN) ? f2bf(W1[(size_t)k1 * HID + c]) : (unsigned short)0;
        w[p] = (unsigned int)lo | ((unsigned int)hi << 16);
    }
    uint4* dstp = (uint4*)(W1s + (size_t)tid * 8);
    uint4 val; val.x = w[0]; val.y = w[1]; val.z = w[2]; val.w = w[3];
    *dstp = val;
}

// ---------------- FAT kernel: gemm blocks [0,gb) || FILL blocks [gb, grid) ---
// Fixed-stride CSR fill needs no counts/scan -> runs concurrently with gemm.
// csr_f[d*CAP + pos] = s, pos = atomicAdd(cnt[d]); overflow -> ovf pairs.
__global__ __launch_bounds__(512, 4) void gemm_fill(const float* __restrict__ x,
                                                    const unsigned short* __restrict__ W1s,
                                                    unsigned short* __restrict__ h, int M,
                                                    const int* __restrict__ src,
                                                    const int* __restrict__ dst, int E,
                                                    int* __restrict__ cnt,
                                                    int* __restrict__ csr_f,
                                                    int* __restrict__ ovf_cnt,
                                                    int2* __restrict__ ovf, int gb) {
    __shared__ unsigned short As[2][8192];
    __shared__ unsigned short Bs[3][8192];

    if (blockIdx.x >= gb) {
        // ---- fill blocks: 512 threads x 8 edges ----
        int bid = blockIdx.x - gb;
        int i = (bid * 512 + (int)threadIdx.x) * 8;
        int lim = min(i + 8, E);
        for (int e = i; e < lim; ++e) {
            int d = dst[e], s = src[e];
            int pos = atomicAdd(&cnt[d], 1);
            if (pos < CAP) csr_f[d * CAP + pos] = s;
            else { int op = atomicAdd(ovf_cnt, 1); ovf[op] = make_int2(d, s); }
        }
        return;
    }

    // ---- gemm blocks (R9/R12-verified pipeline) ----
    const int t = threadIdx.x;
    const int wave = t >> 6, lane = t & 63;
    const int wm = wave >> 1, wn = wave & 1;
    const int r = lane & 15, u = lane >> 4;
    const int rowBase = blockIdx.x * BM;
    f32x4 acc[2][4] = {};

    float4 areg[4];

    auto issueA = [&](int kt) {
        int k0 = kt * BK;
        #pragma unroll
        for (int i = 0; i < 4; ++i) {
            int quad = i * 512 + t;
            int row = quad >> 4, kq = quad & 15;
            int gr = rowBase + row;
            int gk = k0 + kq * 4;
            if (gr < M && gk + 3 < FIN) {
                f32x4u v = __builtin_nontemporal_load((const f32x4u*)(x + (size_t)gr * FIN + gk));
                areg[i].x = v.x; areg[i].y = v.y; areg[i].z = v.z; areg[i].w = v.w;
            } else {
                areg[i].x = (gr < M && gk + 0 < FIN) ? x[(size_t)gr * FIN + gk + 0] : 0.f;
                areg[i].y = (gr < M && gk + 1 < FIN) ? x[(size_t)gr * FIN + gk + 1] : 0.f;
                areg[i].z = (gr < M && gk + 2 < FIN) ? x[(size_t)gr * FIN + gk + 2] : 0.f;
                areg[i].w = (gr < M && gk + 3 < FIN) ? x[(size_t)gr * FIN + gk + 3] : 0.f;
            }
        }
    };
    auto issueB = [&](int kt, int buf) {
        #pragma unroll
        for (int i = 0; i < 2; ++i) {
            const unsigned short* gp = W1s + ((size_t)kt * 1024 + (size_t)(i * 512 + t)) * 8;
            unsigned short* lp = &Bs[buf][(i * 512 + wave * 64) * 8];
            __builtin_amdgcn_global_load_lds(
                (const __attribute__((address_space(1))) unsigned int*)gp,
                (__attribute__((address_space(3))) unsigned int*)lp, 16, 0, 0);
        }
    };
    auto writeA = [&](int buf) {
        #pragma unroll
        for (int i = 0; i < 4; ++i) {
            int quad = i * 512 + t;
            int row = quad >> 4, kq = quad & 15;
            __hip_bfloat162 lo2 = __float22bfloat162_rn(make_float2(areg[i].x, areg[i].y));
            __hip_bfloat162 hi2 = __float22bfloat162_rn(make_float2(areg[i].z, areg[i].w));
            unsigned int ulo, uhi;
            __builtin_memcpy(&ulo, &lo2, 4);
            __builtin_memcpy(&uhi, &hi2, 4);
            unsigned long long pk = ((unsigned long long)uhi << 32) | (unsigned long long)ulo;
            int us = row * 64 + ((kq * 4) ^ ((row & 7) << 3));
            *(unsigned long long*)(&As[buf][us]) = pk;
        }
    };
    auto compute = [&](int abuf, int bbuf) {
        short8_t af[2][2], bfr[2][4];
        #pragma unroll
        for (int ks = 0; ks < 2; ++ks) {
            int g = ks * 4 + u;
            #pragma unroll
            for (int mi = 0; mi < 2; ++mi) {
                int row = wm * 32 + mi * 16 + r;
                int us = row * 64 + ((g * 8) ^ ((row & 7) << 3));
                af[ks][mi] = *(const short8_t*)(&As[abuf][us]);
            }
            #pragma unroll
            for (int ni = 0; ni < 4; ++ni) {
                int c = wn * 64 + ni * 16 + r;
                bfr[ks][ni] = *(const short8_t*)(&Bs[bbuf][g * 1024 + c * 8]);
            }
        }
        #pragma unroll
        for (int ks = 0; ks < 2; ++ks)
            #pragma unroll
            for (int mi = 0; mi < 2; ++mi)
                #pragma unroll
                for (int ni = 0; ni < 4; ++ni)
                    acc[mi][ni] = __builtin_amdgcn_mfma_f32_16x16x32_bf16(af[ks][mi], bfr[ks][ni], acc[mi][ni], 0, 0, 0);
    };

    issueA(0); issueB(0, 0);
    writeA(0);
    issueA(1); issueB(1, 1);
    asm volatile("s_waitcnt vmcnt(6) lgkmcnt(0)" ::: "memory");
    __builtin_amdgcn_sched_barrier(0);
    __builtin_amdgcn_s_barrier();
    __builtin_amdgcn_sched_barrier(0);

    for (int kt = 0; kt < KT1 - 2; ++kt) {
        compute(kt & 1, kt % 3);
        writeA((kt + 1) & 1);
        issueA(kt + 2);
        issueB(kt + 2, (kt + 2) % 3);
        asm volatile("s_waitcnt vmcnt(6) lgkmcnt(0)" ::: "memory");
        __builtin_amdgcn_sched_barrier(0);
        __builtin_amdgcn_s_barrier();
        __builtin_amdgcn_sched_barrier(0);
    }
    {
        const int kt = KT1 - 2;
        compute(kt & 1, kt % 3);
        writeA((kt + 1) & 1);
        __syncthreads();
    }
    compute((KT1 - 1) & 1, (KT1 - 1) % 3);

    #pragma unroll
    for (int mi = 0; mi < 2; ++mi) {
        #pragma unroll
        for (int reg = 0; reg < 4; ++reg) {
            int grow = rowBase + wm * 32 + mi * 16 + u * 4 + reg;
            if (grow < M) {
                #pragma unroll
                for (int ni = 0; ni < 4; ++ni) {
                    int gcol = wn * 64 + ni * 16 + r;
                    h[(size_t)grow * HID + gcol] = f2bf(acc[mi][ni][reg]);
                }
            }
        }
    }
}

// ---------------- self-loop insert + dinv (one thread per node, no atomics) --
__global__ void self_dinv(int* __restrict__ cnt, int* __restrict__ csr_f,
                          float* __restrict__ dinv,
                          int* __restrict__ ovf_cnt, int2* __restrict__ ovf, int n) {
    int i = blockIdx.x * 256 + threadIdx.x;
    if (i >= n) return;
    int c = cnt[i];
    if (c < CAP) csr_f[i * CAP + c] = i;
    else { int op = atomicAdd(ovf_cnt, 1); ovf[op] = make_int2(i, i); }
    cnt[i] = c + 1;
    dinv[i] = rsqrtf((float)(c + 1));
}

// ---------------- Aggregation 1 + bias + relu + @W2 fused ----------------
// list = csr_f[v*CAP .. v*CAP+min(cnt,CAP)) (+ ovf walk if cnt>CAP).
__global__ __launch_bounds__(256) void agg1(const unsigned short* __restrict__ h,
                                            const int* __restrict__ cnt,
                                            const int* __restrict__ csr_f,
                                            const float* __restrict__ dinv,
                                            const float* __restrict__ b1,
                                            const float* __restrict__ W2,
                                            const int* __restrict__ ovf_cnt,
                                            const int2* __restrict__ ovf,
                                            float* __restrict__ h2s, int n) {
    __shared__ float W2s[HID * NCLS];
    for (int i = threadIdx.x; i < HID * NCLS; i += 256) W2s[i] = W2[i];
    __syncthreads();
    int wave = threadIdx.x >> 6, lane = threadIdx.x & 63;
    int v = blockIdx.x * 4 + wave;
    if (v >= n) return;
    const int fr = lane & 15, g = lane >> 4;
    int total = cnt[v];
    int inrow = min(total, CAP);
    const int base = v * CAP;
    float acc[8] = {};
    #pragma unroll 4
    for (int j = g; j < inrow; j += 4) {
        int s = csr_f[base + j];
        float ds = dinv[s];
        uint4 q = *(const uint4*)(h + (size_t)s * HID + fr * 8);
        unsigned int w[4] = {q.x, q.y, q.z, q.w};
        #pragma unroll
        for (int p = 0; p < 4; ++p) {
            acc[p * 2 + 0] += ds * u2f(w[p] << 16);          // low bf16
            acc[p * 2 + 1] += ds * u2f(w[p] & 0xffff0000u);  // high bf16
        }
    }
    if (__builtin_expect(total > CAP, 0) && g == 0) {
        int on = *ovf_cnt;
        for (int k = 0; k < on; ++k) {
            int2 pr = ovf[k];
            if (pr.x == v) {
                int s = pr.y;
                float ds = dinv[s];
                uint4 q = *(const uint4*)(h + (size_t)s * HID + fr * 8);
                unsigned int w[4] = {q.x, q.y, q.z, q.w};
                #pragma unroll
                for (int p = 0; p < 4; ++p) {
                    acc[p * 2 + 0] += ds * u2f(w[p] << 16);
                    acc[p * 2 + 1] += ds * u2f(w[p] & 0xffff0000u);
                }
            }
        }
    }
    #pragma unroll
    for (int e = 0; e < 8; ++e) {
        acc[e] += __shfl_xor(acc[e], 16, 64);
        acc[e] += __shfl_xor(acc[e], 32, 64);
    }
    float dv = dinv[v];
    float p[NCLS];
    #pragma unroll
    for (int c = 0; c < NCLS; ++c) p[c] = 0.f;
    #pragma unroll
    for (int e = 0; e < 8; ++e) {
        int f = fr * 8 + e;
        float val = fmaxf(dv * acc[e] + b1[f], 0.f);
        #pragma unroll
        for (int c = 0; c < NCLS; ++c) p[c] += val * W2s[f * NCLS + c];
    }
    #pragma unroll
    for (int off = 8; off >= 1; off >>= 1)
        #pragma unroll
        for (int c = 0; c < NCLS; ++c)
            p[c] += __shfl_xor(p[c], off, 64);
    if (lane == 0) {
        #pragma unroll
        for (int c = 0; c < NCLS; ++c) h2s[(size_t)v * 8 + c] = dv * p[c];  // pre-scaled
        h2s[(size_t)v * 8 + 7] = 0.f;
    }
}

// ---------------- Aggregation 2 + bias ----------------
__global__ __launch_bounds__(256) void agg2(const float* __restrict__ h2s,
                                            const int* __restrict__ cnt,
                                            const int* __restrict__ csr_f,
                                            const float* __restrict__ dinv,
                                            const float* __restrict__ b2,
                                            const int* __restrict__ ovf_cnt,
                                            const int2* __restrict__ ovf,
                                            float* __restrict__ out, int n) {
    int wave = threadIdx.x >> 6, lane = threadIdx.x & 63;
    int half = lane >> 5;
    int c = lane & 7, g = (lane >> 3) & 3;
    int v = blockIdx.x * 8 + wave * 2 + half;
    if (v >= n) return;
    int total = cnt[v];
    int inrow = min(total, CAP);
    const int base = v * CAP;
    float acc = 0.f;
    #pragma unroll 4
    for (int j = g; j < inrow; j += 4) {
        int s = csr_f[base + j];
        acc += h2s[(size_t)s * 8 + c];
    }
    if (__builtin_expect(total > CAP, 0) && g == 0) {
        int on = *ovf_cnt;
        for (int k = 0; k < on; ++k) {
            int2 pr = ovf[k];
            if (pr.x == v) acc += h2s[(size_t)pr.y * 8 + c];
        }
    }
    acc += __shfl_xor(acc, 8, 64);
    acc += __shfl_xor(acc, 16, 64);
    if (g == 0 && c < NCLS) out[(size_t)v * NCLS + c] = dinv[v] * acc + b2[c];
}

extern "C" void kernel_launch(void* const* d_in, const int* in_sizes, int n_in,
                              void* d_out, int out_size, void* d_ws, size_t ws_size,
                              hipStream_t stream) {
    const float* x  = (const float*)d_in[0];
    const int*   ei = (const int*)d_in[1];    // int64 in reference but JAX x64-off => int32
    const float* W1 = (const float*)d_in[2];
    const float* b1 = (const float*)d_in[3];
    const float* W2 = (const float*)d_in[4];
    const float* b2 = (const float*)d_in[5];
    float* out = (float*)d_out;

    const int N = NNODES;
    const int E = in_sizes[1] / 2;
    const int* src = ei;
    const int* dst = ei + E;
    const int GB = (N + BM - 1) / BM;         // gemm blocks (391)
    const int FB = (E + 4095) / 4096;         // fill blocks (512t x 8 edges)

    char* ws = (char*)d_ws;
    size_t off = 0;
    auto alloc = [&](size_t bytes) {
        void* p = ws + off;
        off += (bytes + 255) & ~(size_t)255;
        return p;
    };
    int*   cnt     = (int*)alloc((size_t)N * 4);
    int*   ovf_cnt = (int*)alloc(4);
    float* dinv    = (float*)alloc((size_t)N * 4);
    int*   csr_f   = (int*)alloc((size_t)N * CAP * 4);
    int2*  ovf     = (int2*)alloc((size_t)4096 * 8);
    unsigned short* W1s = (unsigned short*)alloc((size_t)KT1 * 1024 * 8 * 2);
    unsigned short* h   = (unsigned short*)alloc((size_t)N * HID * 2);
    float* h2s     = (float*)alloc((size_t)N * 8 * 4);

    // zero cnt + ovf_cnt (contiguous allocations)
    hipMemsetAsync(cnt, 0, ((char*)ovf_cnt - (char*)cnt) + 256, stream);
    prep_w1<<<(KT1 * 1024 + 511) / 512, 512, 0, stream>>>(W1, W1s);
    gemm_fill<<<GB + FB, 512, 0, stream>>>(x, W1s, h, N, src, dst, E,
                                           cnt, csr_f, ovf_cnt, ovf, GB);
    self_dinv<<<(N + 255) / 256, 256, 0, stream>>>(cnt, csr_f, dinv, ovf_cnt, ovf, N);
    agg1<<<(N + 3) / 4, 256, 0, stream>>>(h, cnt, csr_f, dinv, b1, W2, ovf_cnt, ovf, h2s, N);
    agg2<<<(N + 7) / 8, 256, 0, stream>>>(h2s, cnt, csr_f, dinv, b2, ovf_cnt, ovf, out, N);
}

// Round 14
// 241.032 us; speedup vs baseline: 2.1827x; 1.0265x over previous
//
#include <hip/hip_runtime.h>
#include <hip/hip_bf16.h>

typedef __attribute__((ext_vector_type(8))) short short8_t;
typedef __attribute__((ext_vector_type(4))) float f32x4;
typedef float f32x4u __attribute__((ext_vector_type(4), aligned(4)));  // 4B-aligned vector load

#define NNODES 50000
#define FIN 1433
#define HID 128
#define NCLS 7
#define KT1 45          // ceil(1433/32)
#define BK 32
#define BM 128
#define CAP 96          // fixed CSR slots/node; Poisson(32) => P(deg>96) ~ 0; exact via ovf
#define GSTR 1040       // A LDS g-stride in ushorts (128*8 + 16 pad -> conflict-free)

static __device__ __forceinline__ unsigned short f2bf(float f) {
    union { float f; unsigned int u; } v; v.f = f;
    unsigned int u = v.u;
    u += 0x7FFFu + ((u >> 16) & 1u);   // round-to-nearest-even
    return (unsigned short)(u >> 16);
}
static __device__ __forceinline__ float u2f(unsigned int u) {
    union { unsigned int u; float f; } v; v.u = u; return v.f;
}

// ---------------- W1 pack: W1[FIN][HID] f32 -> W1s[KT1][512 segs][8 bf16]
// seg = g*128 + c (g = k-octet within BK=32 tile); LDS-tile order.
__global__ void prep_w1(const float* __restrict__ W1, unsigned short* __restrict__ W1s) {
    int tid = blockIdx.x * 512 + threadIdx.x;
    if (tid >= KT1 * 512) return;
    int kt = tid >> 9, seg = tid & 511;
    int c = seg & 127, g = seg >> 7;
    int kb = kt * BK + g * 8;
    unsigned int w[4];
    #pragma unroll
    for (int p = 0; p < 4; ++p) {
        int k0 = kb + p * 2, k1 = kb + p * 2 + 1;
        unsigned short lo = (k0 < FIN) ? f2bf(W1[(size_t)k0 * HID + c]) : (unsigned short)0;
        unsigned short hi = (k1 < FIN) ? f2bf(W1[(size_t)k1 * HID + c]) : (unsigned short)0;
        w[p] = (unsigned int)lo | ((unsigned int)hi << 16);
    }
    uint4* dstp = (uint4*)(W1s + (size_t)tid * 8);
    uint4 val; val.x = w[0]; val.y = w[1]; val.z = w[2]; val.w = w[3];
    *dstp = val;
}

// ---------------- FAT kernel: gemm blocks [0,gb) || FILL blocks [gb, grid) ---
// GEMM: BM=128, BK=32, 512t. LDS 41KB -> 3 blocks/CU; launch_bounds(512,8)
// forces VGPR<=64 -> 24 waves/CU (75% occ). Counted vmcnt(3) pipeline.
// FILL: fixed-stride CSR scatter (no counts/scan needed).
__global__ __launch_bounds__(512, 8) void gemm_fill(const float* __restrict__ x,
                                                    const unsigned short* __restrict__ W1s,
                                                    unsigned short* __restrict__ h, int M,
                                                    const int* __restrict__ src,
                                                    const int* __restrict__ dst, int E,
                                                    int* __restrict__ cnt,
                                                    int* __restrict__ csr_f,
                                                    int* __restrict__ ovf_cnt,
                                                    int2* __restrict__ ovf, int gb) {
    __shared__ unsigned short As[2][4160];   // [g^(row&3)][row][8], GSTR=1040
    __shared__ unsigned short Bs[3][4096];   // [g 4][c 128][8] linear (gload_lds)

    if (blockIdx.x >= gb) {
        // ---- fill blocks: 512 threads x 8 edges ----
        int bid = blockIdx.x - gb;
        int i = (bid * 512 + (int)threadIdx.x) * 8;
        int lim = min(i + 8, E);
        for (int e = i; e < lim; ++e) {
            int d = dst[e], s = src[e];
            int pos = atomicAdd(&cnt[d], 1);
            if (pos < CAP) csr_f[d * CAP + pos] = s;
            else { int op = atomicAdd(ovf_cnt, 1); ovf[op] = make_int2(d, s); }
        }
        return;
    }

    // ---- gemm blocks ----
    const int t = threadIdx.x;
    const int wave = t >> 6, lane = t & 63;
    const int wm = wave >> 1, wn = wave & 1;
    const int r = lane & 15, u = lane >> 4;       // u in 0..3 = K-octet & row-quad
    const int rowBase = blockIdx.x * BM;
    f32x4 acc[2][4] = {};

    float4 areg[2];

    auto issueA = [&](int kt) {
        int k0 = kt * BK;
        #pragma unroll
        for (int i = 0; i < 2; ++i) {
            int quad = i * 512 + t;
            int row = quad >> 3, kq = quad & 7;
            int gr = min(rowBase + row, M - 1);   // clamp; OOB rows unstored
            int gk = k0 + kq * 4;                 // in-bounds for kt <= 43
            f32x4u v = *(const f32x4u*)(x + (size_t)gr * FIN + gk);
            areg[i].x = v.x; areg[i].y = v.y; areg[i].z = v.z; areg[i].w = v.w;
        }
    };
    auto issueA_tail = [&]() {                    // kt=44: k 1408..1439, guard FIN
        #pragma unroll
        for (int i = 0; i < 2; ++i) {
            int quad = i * 512 + t;
            int row = quad >> 3, kq = quad & 7;
            int gr = min(rowBase + row, M - 1);
            int gk = 1408 + kq * 4;
            const float* p = x + (size_t)gr * FIN;
            areg[i].x = (gk + 0 < FIN) ? p[gk + 0] : 0.f;
            areg[i].y = (gk + 1 < FIN) ? p[gk + 1] : 0.f;
            areg[i].z = (gk + 2 < FIN) ? p[gk + 2] : 0.f;
            areg[i].w = (gk + 3 < FIN) ? p[gk + 3] : 0.f;
        }
    };
    auto issueB = [&](int kt, int buf) {
        const unsigned short* gp = W1s + ((size_t)kt * 512 + t) * 8;
        unsigned short* lp = &Bs[buf][(wave * 64) * 8];
        __builtin_amdgcn_global_load_lds(
            (const __attribute__((address_space(1))) unsigned int*)gp,
            (__attribute__((address_space(3))) unsigned int*)lp, 16, 0, 0);
    };
    auto writeA = [&](int buf) {
        #pragma unroll
        for (int i = 0; i < 2; ++i) {
            int quad = i * 512 + t;
            int row = quad >> 3, kq = quad & 7;
            __hip_bfloat162 lo2 = __float22bfloat162_rn(make_float2(areg[i].x, areg[i].y));
            __hip_bfloat162 hi2 = __float22bfloat162_rn(make_float2(areg[i].z, areg[i].w));
            unsigned int ulo, uhi;
            __builtin_memcpy(&ulo, &lo2, 4);
            __builtin_memcpy(&uhi, &hi2, 4);
            unsigned long long pk = ((unsigned long long)uhi << 32) | (unsigned long long)ulo;
            int g = kq >> 1, half = kq & 1;
            int us = ((g ^ (row & 3)) * GSTR) + row * 8 + half * 4;
            *(unsigned long long*)(&As[buf][us]) = pk;
        }
    };
    auto compute = [&](int kt) {
        const int abuf = kt & 1, bbuf = kt % 3;
        short8_t af[2], bfr[4];
        #pragma unroll
        for (int mi = 0; mi < 2; ++mi) {
            int row = wm * 32 + mi * 16 + r;
            int us = ((u ^ (row & 3)) * GSTR) + row * 8;
            af[mi] = *(const short8_t*)(&As[abuf][us]);
        }
        #pragma unroll
        for (int ni = 0; ni < 4; ++ni) {
            int c = wn * 64 + ni * 16 + r;
            bfr[ni] = *(const short8_t*)(&Bs[bbuf][u * 1024 + c * 8]);
        }
        #pragma unroll
        for (int mi = 0; mi < 2; ++mi)
            #pragma unroll
            for (int ni = 0; ni < 4; ++ni)
                acc[mi][ni] = __builtin_amdgcn_mfma_f32_16x16x32_bf16(af[mi], bfr[ni], acc[mi][ni], 0, 0, 0);
    };

    // prologue: tile 0 staged; tile 1 in flight
    issueA(0); issueB(0, 0);
    writeA(0);                       // implicit wait on A(0)
    issueA(1); issueB(1, 1);
    asm volatile("s_waitcnt vmcnt(3) lgkmcnt(0)" ::: "memory");  // retire B(0)
    __builtin_amdgcn_sched_barrier(0);
    __builtin_amdgcn_s_barrier();
    __builtin_amdgcn_sched_barrier(0);

    // main loop: kt = 0..42-1 (issues up to tile 43; tiles 0..43 all k-in-bounds)
    for (int kt = 0; kt < KT1 - 3; ++kt) {
        compute(kt);
        writeA((kt + 1) & 1);        // waits A(t+1)
        issueA(kt + 2);
        issueB(kt + 2, (kt + 2) % 3);
        // outstanding: B(t+1)1 + A(t+2)2 + B(t+2)1 = 4 -> retire B(t+1)
        asm volatile("s_waitcnt vmcnt(3) lgkmcnt(0)" ::: "memory");
        __builtin_amdgcn_sched_barrier(0);
        __builtin_amdgcn_s_barrier();
        __builtin_amdgcn_sched_barrier(0);
    }
    // kt = 42: last counted iter's compute+write; then leave counted regime
    {
        compute(KT1 - 3);            // 42
        writeA((KT1 - 2) & 1);       // A(43) -> As[1]
        __syncthreads();
    }
    // stage guarded tail tile 44 (outside counted regime)
    issueA_tail();
    issueB(KT1 - 1, (KT1 - 1) % 3);  // B(44) -> Bs[2]
    writeA((KT1 - 1) & 1);           // A(44) -> As[0]
    __syncthreads();
    compute(KT1 - 2);                // 43
    compute(KT1 - 1);                // 44

    // epilogue: C layout col=lane&15, row=(lane>>4)*4+reg (raw, no dinv)
    #pragma unroll
    for (int mi = 0; mi < 2; ++mi) {
        #pragma unroll
        for (int reg = 0; reg < 4; ++reg) {
            int grow = rowBase + wm * 32 + mi * 16 + u * 4 + reg;
            if (grow < M) {
                #pragma unroll
                for (int ni = 0; ni < 4; ++ni) {
                    int gcol = wn * 64 + ni * 16 + r;
                    h[(size_t)grow * HID + gcol] = f2bf(acc[mi][ni][reg]);
                }
            }
        }
    }
}

// ---------------- self-loop insert + dinv (one thread per node) --------------
__global__ void self_dinv(int* __restrict__ cnt, int* __restrict__ csr_f,
                          float* __restrict__ dinv,
                          int* __restrict__ ovf_cnt, int2* __restrict__ ovf, int n) {
    int i = blockIdx.x * 256 + threadIdx.x;
    if (i >= n) return;
    int c = cnt[i];
    if (c < CAP) csr_f[i * CAP + c] = i;
    else { int op = atomicAdd(ovf_cnt, 1); ovf[op] = make_int2(i, i); }
    cnt[i] = c + 1;
    dinv[i] = rsqrtf((float)(c + 1));
}

// ---------------- Aggregation 1 + bias + relu + @W2 fused ----------------
__global__ __launch_bounds__(256) void agg1(const unsigned short* __restrict__ h,
                                            const int* __restrict__ cnt,
                                            const int* __restrict__ csr_f,
                                            const float* __restrict__ dinv,
                                            const float* __restrict__ b1,
                                            const float* __restrict__ W2,
                                            const int* __restrict__ ovf_cnt,
                                            const int2* __restrict__ ovf,
                                            float* __restrict__ h2s, int n) {
    __shared__ float W2s[HID * NCLS];
    for (int i = threadIdx.x; i < HID * NCLS; i += 256) W2s[i] = W2[i];
    __syncthreads();
    int wave = threadIdx.x >> 6, lane = threadIdx.x & 63;
    int v = blockIdx.x * 4 + wave;
    if (v >= n) return;
    const int fr = lane & 15, g = lane >> 4;
    int total = cnt[v];
    int inrow = min(total, CAP);
    const int base = v * CAP;
    float acc[8] = {};
    #pragma unroll 4
    for (int j = g; j < inrow; j += 4) {
        int s = csr_f[base + j];
        float ds = dinv[s];
        uint4 q = *(const uint4*)(h + (size_t)s * HID + fr * 8);
        unsigned int w[4] = {q.x, q.y, q.z, q.w};
        #pragma unroll
        for (int p = 0; p < 4; ++p) {
            acc[p * 2 + 0] += ds * u2f(w[p] << 16);          // low bf16
            acc[p * 2 + 1] += ds * u2f(w[p] & 0xffff0000u);  // high bf16
        }
    }
    if (__builtin_expect(total > CAP, 0) && g == 0) {
        int on = *ovf_cnt;
        for (int k = 0; k < on; ++k) {
            int2 pr = ovf[k];
            if (pr.x == v) {
                int s = pr.y;
                float ds = dinv[s];
                uint4 q = *(const uint4*)(h + (size_t)s * HID + fr * 8);
                unsigned int w[4] = {q.x, q.y, q.z, q.w};
                #pragma unroll
                for (int p = 0; p < 4; ++p) {
                    acc[p * 2 + 0] += ds * u2f(w[p] << 16);
                    acc[p * 2 + 1] += ds * u2f(w[p] & 0xffff0000u);
                }
            }
        }
    }
    #pragma unroll
    for (int e = 0; e < 8; ++e) {
        acc[e] += __shfl_xor(acc[e], 16, 64);
        acc[e] += __shfl_xor(acc[e], 32, 64);
    }
    float dv = dinv[v];
    float p[NCLS];
    #pragma unroll
    for (int c = 0; c < NCLS; ++c) p[c] = 0.f;
    #pragma unroll
    for (int e = 0; e < 8; ++e) {
        int f = fr * 8 + e;
        float val = fmaxf(dv * acc[e] + b1[f], 0.f);
        #pragma unroll
        for (int c = 0; c < NCLS; ++c) p[c] += val * W2s[f * NCLS + c];
    }
    #pragma unroll
    for (int off = 8; off >= 1; off >>= 1)
        #pragma unroll
        for (int c = 0; c < NCLS; ++c)
            p[c] += __shfl_xor(p[c], off, 64);
    if (lane == 0) {
        #pragma unroll
        for (int c = 0; c < NCLS; ++c) h2s[(size_t)v * 8 + c] = dv * p[c];  // pre-scaled
        h2s[(size_t)v * 8 + 7] = 0.f;
    }
}

// ---------------- Aggregation 2 + bias ----------------
__global__ __launch_bounds__(256) void agg2(const float* __restrict__ h2s,
                                            const int* __restrict__ cnt,
                                            const int* __restrict__ csr_f,
                                            const float* __restrict__ dinv,
                                            const float* __restrict__ b2,
                                            const int* __restrict__ ovf_cnt,
                                            const int2* __restrict__ ovf,
                                            float* __restrict__ out, int n) {
    int wave = threadIdx.x >> 6, lane = threadIdx.x & 63;
    int half = lane >> 5;
    int c = lane & 7, g = (lane >> 3) & 3;
    int v = blockIdx.x * 8 + wave * 2 + half;
    if (v >= n) return;
    int total = cnt[v];
    int inrow = min(total, CAP);
    const int base = v * CAP;
    float acc = 0.f;
    #pragma unroll 4
    for (int j = g; j < inrow; j += 4) {
        int s = csr_f[base + j];
        acc += h2s[(size_t)s * 8 + c];
    }
    if (__builtin_expect(total > CAP, 0) && g == 0) {
        int on = *ovf_cnt;
        for (int k = 0; k < on; ++k) {
            int2 pr = ovf[k];
            if (pr.x == v) acc += h2s[(size_t)pr.y * 8 + c];
        }
    }
    acc += __shfl_xor(acc, 8, 64);
    acc += __shfl_xor(acc, 16, 64);
    if (g == 0 && c < NCLS) out[(size_t)v * NCLS + c] = dinv[v] * acc + b2[c];
}

extern "C" void kernel_launch(void* const* d_in, const int* in_sizes, int n_in,
                              void* d_out, int out_size, void* d_ws, size_t ws_size,
                              hipStream_t stream) {
    const float* x  = (const float*)d_in[0];
    const int*   ei = (const int*)d_in[1];    // int64 in reference but JAX x64-off => int32
    const float* W1 = (const float*)d_in[2];
    const float* b1 = (const float*)d_in[3];
    const float* W2 = (const float*)d_in[4];
    const float* b2 = (const float*)d_in[5];
    float* out = (float*)d_out;

    const int N = NNODES;
    const int E = in_sizes[1] / 2;
    const int* src = ei;
    const int* dst = ei + E;
    const int GB = (N + BM - 1) / BM;         // gemm blocks (391)
    const int FB = (E + 4095) / 4096;         // fill blocks (512t x 8 edges)

    char* ws = (char*)d_ws;
    size_t off = 0;
    auto alloc = [&](size_t bytes) {
        void* p = ws + off;
        off += (bytes + 255) & ~(size_t)255;
        return p;
    };
    int*   cnt     = (int*)alloc((size_t)N * 4);
    int*   ovf_cnt = (int*)alloc(4);
    float* dinv    = (float*)alloc((size_t)N * 4);
    int*   csr_f   = (int*)alloc((size_t)N * CAP * 4);
    int2*  ovf     = (int2*)alloc((size_t)4096 * 8);
    unsigned short* W1s = (unsigned short*)alloc((size_t)KT1 * 512 * 8 * 2);
    unsigned short* h   = (unsigned short*)alloc((size_t)N * HID * 2);
    float* h2s     = (float*)alloc((size_t)N * 8 * 4);

    // zero cnt + ovf_cnt (contiguous allocations)
    hipMemsetAsync(cnt, 0, ((char*)ovf_cnt - (char*)cnt) + 256, stream);
    prep_w1<<<(KT1 * 512 + 511) / 512, 512, 0, stream>>>(W1, W1s);
    gemm_fill<<<GB + FB, 512, 0, stream>>>(x, W1s, h, N, src, dst, E,
                                           cnt, csr_f, ovf_cnt, ovf, GB);
    self_dinv<<<(N + 255) / 256, 256, 0, stream>>>(cnt, csr_f, dinv, ovf_cnt, ovf, N);
    agg1<<<(N + 3) / 4, 256, 0, stream>>>(h, cnt, csr_f, dinv, b1, W2, ovf_cnt, ovf, h2s, N);
    agg2<<<(N + 7) / 8, 256, 0, stream>>>(h2s, cnt, csr_f, dinv, b2, ovf_cnt, ovf, out, N);
}